// Round 10
// baseline (317.396 us; speedup 1.0000x reference)
//
#include <hip/hip_runtime.h>
#include <hip/hip_bf16.h>
#include <math.h>

// Problem constants
#define PTOT 36864          // Bsz*Hs*Ws = 16*48*48
#define DIM 768
#define NCOLS 640           // packed projection columns (613 used, padded)
#define IMG 2304            // 48*48
#define PROJ_ROWS 616       // projT rows actually allocated (612 used)
#define KSTEPS 24           // 768/32
#define NPBLK 288           // PTOT/128

typedef unsigned short ushort_t;
typedef unsigned int uint_t;
typedef __attribute__((ext_vector_type(8))) short bfx8;
typedef __attribute__((ext_vector_type(4))) float f32x4;

#define MFMA_BF16(a, b, c) __builtin_amdgcn_mfma_f32_16x16x32_bf16((a), (b), (c), 0, 0, 0)

// counted VMEM wait (T4): wait until <= N of this wave's VMEM ops outstanding
#define VM_WAIT(N) asm volatile("s_waitcnt vmcnt(" #N ")" ::: "memory")

__device__ __forceinline__ float sigmoidf_(float v) { return 1.f / (1.f + __expf(-v)); }
__device__ __forceinline__ float siluf_(float v)    { return v   / (1.f + __expf(-v)); }
__device__ __forceinline__ float rfl(float v) {
  return __int_as_float(__builtin_amdgcn_readfirstlane(__float_as_int(v)));
}

// async global->LDS, 16B per lane; LDS dest = wave-uniform base + lane*16
typedef __attribute__((address_space(3))) unsigned int lds_uint;
typedef __attribute__((address_space(1))) const unsigned int g_uint;
__device__ __forceinline__ void glds16(const void* gsrc, void* ldst) {
  __builtin_amdgcn_global_load_lds((g_uint*)gsrc, (lds_uint*)ldst, 16, 0, 0);
}

// split a pair of f32 into packed bf16 hi word + bf16 lo word (cvt_pk-based)
__device__ __forceinline__ void split2(float a, float b, uint_t& hw, uint_t& lw) {
  __hip_bfloat162 hh = __float22bfloat162_rn(make_float2(a, b));
  uint_t hu; __builtin_memcpy(&hu, &hh, 4);
  float ha = __uint_as_float(hu << 16);
  float hb = __uint_as_float(hu & 0xffff0000u);
  __hip_bfloat162 ll = __float22bfloat162_rn(make_float2(a - ha, b - hb));
  uint_t lu; __builtin_memcpy(&lu, &ll, 4);
  hw = hu; lw = lu;
}
__device__ __forceinline__ uint_t cvt2_hi(float a, float b) {
  __hip_bfloat162 hh = __float22bfloat162_rn(make_float2(a, b));
  uint_t hu; __builtin_memcpy(&hu, &hh, 4);
  return hu;
}
__device__ __forceinline__ void split8_fast(const float* f, uint4& hi, uint4& lo) {
  uint_t* Hp = (uint_t*)&hi;
  uint_t* Lp = (uint_t*)&lo;
#pragma unroll
  for (int q = 0; q < 4; ++q) split2(f[2 * q], f[2 * q + 1], Hp[q], Lp[q]);
}
__device__ __forceinline__ void cvt8_hi(const float* f, uint4& hi) {
  uint_t* Hp = (uint_t*)&hi;
#pragma unroll
  for (int q = 0; q < 4; ++q) Hp[q] = cvt2_hi(f[2 * q], f[2 * q + 1]);
}

// ---------------------------------------------------------------------------
// pack: projection weights -> split-bf16 [c][k]; W_out^T -> plain bf16 [j][k];
// fused bias.
// ---------------------------------------------------------------------------
__global__ void pack_kernel(
    const float* __restrict__ W_B, const float* __restrict__ W_C,
    const float* __restrict__ W_dec, const float* __restrict__ W_th,
    const float* __restrict__ W_X, const float* __restrict__ W_lam,
    const float* __restrict__ b_B, const float* __restrict__ b_C,
    const float* __restrict__ b_dec, const float* __restrict__ b_th,
    const float* __restrict__ b_X, const float* __restrict__ b_lam,
    const float* __restrict__ B_bias, const float* __restrict__ C_bias,
    const float* __restrict__ W_out,
    ushort_t* __restrict__ WhiT, ushort_t* __restrict__ WloT,
    ushort_t* __restrict__ WoT, float* __restrict__ bias_all) {
  int idx = blockIdx.x * 256 + threadIdx.x;
  const int NW = NCOLS * DIM;          // 491520
  const int NWO = DIM * 256;           // 196608
  if (idx < NW) {
    int c = idx / DIM, k = idx - c * DIM;
    float v;
    if      (c < 256) v = W_B[k * 256 + c];
    else if (c < 512) v = W_C[k * 256 + (c - 256)];
    else if (c < 576) v = W_dec[k * 64 + (c - 512)];
    else if (c < 608) v = W_th[k * 32 + (c - 576)];
    else if (c < 612) v = W_X[k * 4 + (c - 608)];
    else if (c == 612) v = W_lam[k];
    else v = 0.f;
    uint_t hw, lw;
    split2(v, 0.f, hw, lw);
    WhiT[idx] = (ushort_t)(hw & 0xffffu);
    WloT[idx] = (ushort_t)(lw & 0xffffu);
  } else if (idx < NW + NWO) {
    int t = idx - NW;
    int j = t / 256, k = t - j * 256;
    WoT[t] = (ushort_t)(cvt2_hi(W_out[k * DIM + j], 0.f) & 0xffffu);
  }
  if (idx < NCOLS) {
    int c = idx;
    float v;
    if      (c < 256) v = b_B[c] + B_bias[c];
    else if (c < 512) v = b_C[c - 256] + C_bias[c - 256];
    else if (c < 576) v = b_dec[c - 512];
    else if (c < 608) v = b_th[c - 576];
    else if (c < 612) v = b_X[c - 608];
    else if (c == 612) v = b_lam[0];
    else v = 0.f;
    bias_all[c] = v;
  }
}

// ---------------------------------------------------------------------------
// GEMM A: glds staging (round-9 row-major + XOR maps) + T4 async pipeline:
// 3 LDS buffers, 2-deep prefetch, counted vmcnt, raw s_barrier (one/k-step).
//   HEAVY=0: c-blocks 0-3 (B,C), plain bf16, 16 MFMA/kstep, 6 loads/stage.
//   HEAVY=1: c-block 4, split-bf16, 48 MFMA/kstep, 8 loads/stage.
// ---------------------------------------------------------------------------
template <int HEAVY>
__global__ __launch_bounds__(256) void gemm_proj_glds(
    const float* __restrict__ x, const ushort_t* __restrict__ WhiT,
    const ushort_t* __restrict__ WloT, const float* __restrict__ biasall,
    float* __restrict__ projT) {
  __shared__ ushort_t Ash[3][4096];                       // W hi tiles
  __shared__ ushort_t Asl[HEAVY ? 3 : 1][HEAVY ? 4096 : 4];
  __shared__ float    Bsf[3][4096];                       // x f32 tiles
  const int tid = threadIdx.x;
  const int lane = tid & 63, wv = tid >> 6;
  const int wr = wv >> 1, wc = wv & 1;
  const int lk = lane >> 4, lm = lane & 15;

  int cblk, pblk;
  if (HEAVY) {
    int lin = blockIdx.x;                  // 0..287, 288 = 8*36
    int id2 = (lin & 7) * 36 + (lin >> 3);
    cblk = 4; pblk = id2;
  } else {
    int lin = blockIdx.x;                  // 0..1151, 1152 = 8*144
    int id2 = (lin & 7) * 144 + (lin >> 3);
    cblk = id2 & 3; pblk = id2 >> 2;       // cblk fastest -> x L2 reuse per XCD
  }
  const int c0 = cblk * 128, p0 = pblk * 128;

  f32x4 acc[4][4];
#pragma unroll
  for (int i = 0; i < 4; ++i)
#pragma unroll
    for (int j = 0; j < 4; ++j) acc[i][j] = (f32x4)0.f;

  auto stage = [&](int buf, int kidx) {
    const int k0 = kidx * 32;
    // W hi: 512 chunks, m = row*4 + sp; 4 lanes cover one 64B row
#pragma unroll
    for (int j = 0; j < 2; ++j) {
      int mb = __builtin_amdgcn_readfirstlane(wv * 128 + j * 64);
      int m = mb + lane;
      int row = m >> 2, sp = m & 3;
      int g = sp ^ ((row >> 1) & 3);
      glds16(&WhiT[(size_t)(c0 + row) * DIM + k0 + g * 8],
             (void*)&Ash[buf][mb * 8]);
    }
    if (HEAVY) {
#pragma unroll
      for (int j = 0; j < 2; ++j) {
        int mb = __builtin_amdgcn_readfirstlane(wv * 128 + j * 64);
        int m = mb + lane;
        int row = m >> 2, sp = m & 3;
        int g = sp ^ ((row >> 1) & 3);
        glds16(&WloT[(size_t)(c0 + row) * DIM + k0 + g * 8],
               (void*)&Asl[buf][mb * 8]);
      }
    }
    // x f32: 1024 chunks, m = row*8 + sp; 8 lanes cover one 128B row
#pragma unroll
    for (int j = 0; j < 4; ++j) {
      int mb = __builtin_amdgcn_readfirstlane(wv * 256 + j * 64);
      int m = mb + lane;
      int row = m >> 3, sp = m & 7;
      int g = sp ^ (row & 7);
      glds16(&x[(size_t)(p0 + row) * DIM + k0 + g * 4],
             (void*)&Bsf[buf][mb * 4]);
    }
  };

  stage(0, 0);
  stage(1, 1);

  for (int kidx = 0; kidx < KSTEPS; ++kidx) {
    const int cur = kidx % 3;
    // wait for stage(kidx) only; stage(kidx+1) stays in flight
    if (kidx < KSTEPS - 1) {
      if (HEAVY) { VM_WAIT(8); } else { VM_WAIT(6); }
    } else {
      VM_WAIT(0);
    }
    __builtin_amdgcn_s_barrier();
    __builtin_amdgcn_sched_barrier(0);
    // issue stage(kidx+2) into buffer (kidx-1)%3 (safe: compute(kidx-1) done)
    int nk = kidx + 2;
    if (nk < KSTEPS) stage(nk % 3, nk);

    bfx8 ah[4], al[4];
#pragma unroll
    for (int f = 0; f < 4; ++f) {
      int row = wr * 64 + f * 16 + lm;
      int sp = lk ^ ((row >> 1) & 3);
      int idx = (row * 4 + sp) * 8;
      ah[f] = *(const bfx8*)&Ash[cur][idx];
      if (HEAVY) al[f] = *(const bfx8*)&Asl[cur][idx];
    }
    bfx8 bh[4], bl[4];
#pragma unroll
    for (int f = 0; f < 4; ++f) {
      int row = wc * 64 + f * 16 + lm;
      int sp0 = (2 * lk)     ^ (row & 7);
      int sp1 = (2 * lk + 1) ^ (row & 7);
      float fv[8];
      *(float4*)&fv[0] = *(const float4*)&Bsf[cur][(row * 8 + sp0) * 4];
      *(float4*)&fv[4] = *(const float4*)&Bsf[cur][(row * 8 + sp1) * 4];
      if (HEAVY) {
        uint4 hv, lv;
        split8_fast(fv, hv, lv);
        bh[f] = *(bfx8*)&hv;
        bl[f] = *(bfx8*)&lv;
      } else {
        uint4 hv;
        cvt8_hi(fv, hv);
        bh[f] = *(bfx8*)&hv;
      }
    }
#pragma unroll
    for (int i = 0; i < 4; ++i)
#pragma unroll
      for (int j = 0; j < 4; ++j) {
        acc[i][j] = MFMA_BF16(ah[i], bh[j], acc[i][j]);
        if (HEAVY) {
          acc[i][j] = MFMA_BF16(al[i], bh[j], acc[i][j]);
          acc[i][j] = MFMA_BF16(ah[i], bl[j], acc[i][j]);
        }
      }
  }

#pragma unroll
  for (int i = 0; i < 4; ++i) {
#pragma unroll
    for (int r = 0; r < 4; ++r) {
      int c = c0 + wr * 64 + i * 16 + lk * 4 + r;
      if (c >= PROJ_ROWS) continue;
      float bia = biasall[c];
      bool do_silu = (c < 512) || (c >= 608 && c < 612);
      bool do_sig  = (c >= 512 && c < 576) || (c == 612);
#pragma unroll
      for (int j = 0; j < 4; ++j) {
        float z = acc[i][j][r] + bia;
        if (do_silu) z = siluf_(z);
        else if (do_sig) z = sigmoidf_(z);
        projT[(size_t)c * PTOT + p0 + wc * 64 + j * 16 + lm] = z;
      }
    }
  }
}

// ---------------------------------------------------------------------------
// Iteration kernel: one block per (n-pair, r, batch), 12 iterations fused.
// ---------------------------------------------------------------------------
__global__ __launch_bounds__(256) void iter_kernel(
    const float* __restrict__ projT, const float* __restrict__ conv_w,
    const float* __restrict__ conv_b, float* __restrict__ HgF) {
  const int n2 = blockIdx.x;   // channel pair 0..31
  const int r  = blockIdx.y;   // 0..3
  const int b  = blockIdx.z;   // 0..15
  const int n0 = 2 * n2, n1 = n0 + 1;
  const int tid = threadIdx.x;
  const int bh = tid >> 4, bw = tid & 15;   // 3x3 strip coords
  const int pbase = b * IMG;

  __shared__ float2 HS[2][50 * 51];   // [buf][(h+1)*51 + (w+1)], zero halo

  float w0[9], w1[9];
#pragma unroll
  for (int t = 0; t < 9; ++t) {
    w0[t] = rfl(conv_w[t * 64 + n0]);
    w1[t] = rfl(conv_w[t * 64 + n1]);
  }
  const float cvb0 = rfl(conv_b[n0]), cvb1 = rfl(conv_b[n1]);

  {
    float4 zz = {0.f, 0.f, 0.f, 0.f};
    float4* z = (float4*)&HS[0][0];
#pragma unroll
    for (int u = 0; u < 10; ++u) {
      int q = tid + 256 * u;
      if (q < 2550) z[q] = zz;
    }
  }

  const float* rowB0 = projT + (size_t)(n0 * 4 + r) * PTOT + pbase;
  const float* rowB1 = projT + (size_t)(n1 * 4 + r) * PTOT + pbase;
  const float* rowC0 = projT + (size_t)(256 + n0 * 4 + r) * PTOT + pbase;
  const float* rowC1 = projT + (size_t)(256 + n1 * 4 + r) * PTOT + pbase;
  const float* rowA0 = projT + (size_t)(512 + n0) * PTOT + pbase;
  const float* rowA1 = projT + (size_t)(512 + n1) * PTOT + pbase;
  const float* rowTh = projT + (size_t)(576 + n2) * PTOT + pbase;
  const float* rowXv = projT + (size_t)(608 + r) * PTOT + pbase;
  const float* rowGm = projT + (size_t)612 * PTOT + pbase;

  float be0[9], be1[9], cb[9], sb[9], al0[9], al1[9], gmv[9];
#pragma unroll
  for (int s = 0; s < 9; ++s) {
    int dy = s / 3, dx = s - 3 * dy;
    int i = (3 * bh + dy) * 48 + 3 * bw + dx;
    float sn, cn;
    __sincosf(rowTh[i], &sn, &cn);
    cb[s] = cn; sb[s] = sn;
    float B0 = rowB0[i], B1 = rowB1[i], X = rowXv[i];
    be0[s] = (B0 * cn - B1 * sn) * X;   // inj at angle theta (iteration 0)
    be1[s] = (B0 * sn + B1 * cn) * X;
    al0[s] = rowA0[i]; al1[s] = rowA1[i];
    gmv[s] = rowGm[i];
  }
  __syncthreads();

  int cur = 0;
  for (int it = 0; it < 12; ++it) {
    float a0[9], a1[9];
#pragma unroll
    for (int s = 0; s < 9; ++s) { a0[s] = cvb0; a1[s] = cvb1; }
#pragma unroll
    for (int yy = 0; yy < 5; ++yy) {
      float2 row[5];
#pragma unroll
      for (int xx = 0; xx < 5; ++xx)
        row[xx] = HS[cur][(3 * bh + yy) * 51 + 3 * bw + xx];
#pragma unroll
      for (int dy = 0; dy < 3; ++dy) {
        int ty = yy - dy;
        if (ty < 0 || ty > 2) continue;
#pragma unroll
        for (int dx = 0; dx < 3; ++dx)
#pragma unroll
          for (int tx = 0; tx < 3; ++tx) {
            a0[dy * 3 + dx] += row[dx + tx].x * w0[ty * 3 + tx];
            a1[dy * 3 + dx] += row[dx + tx].y * w1[ty * 3 + tx];
          }
      }
    }
#pragma unroll
    for (int s = 0; s < 9; ++s) {
      int dy = s / 3, dx = s - 3 * dy;
      float h0, h1;
      if (it == 0) {
        h0 = al0[s] * a0[s] + be0[s];
        h1 = al1[s] * a1[s] + be1[s];
      } else {
        float p0 = be0[s] * cb[s] + be1[s] * sb[s];
        float p1 = be1[s] * cb[s] - be0[s] * sb[s];
        float g = gmv[s];
        h0 = al0[s] * (a0[s] + (1.f - g) * p0) + g * be0[s];
        h1 = al1[s] * (a1[s] + (1.f - g) * p1) + g * be1[s];
      }
      float2 hw; hw.x = h0; hw.y = h1;
      HS[cur ^ 1][(3 * bh + dy + 1) * 51 + (3 * bw + dx + 1)] = hw;
      if (it < 11) {
        float nb0 = be0[s] * cb[s] - be1[s] * sb[s];
        float nb1 = be0[s] * sb[s] + be1[s] * cb[s];
        be0[s] = nb0; be1[s] = nb1;
      }
    }
    __syncthreads();
    cur ^= 1;
  }

  float* outRow0 = HgF + (size_t)(r * 64 + n0) * PTOT + pbase;
  float* outRow1 = HgF + (size_t)(r * 64 + n1) * PTOT + pbase;
#pragma unroll
  for (int s = 0; s < 9; ++s) {
    int dy = s / 3, dx = s - 3 * dy;
    int i = (3 * bh + dy) * 48 + 3 * bw + dx;
    float c2 = cb[s] * cb[s] - sb[s] * sb[s], s2 = 2.f * cb[s] * sb[s];
    float c4 = c2 * c2 - s2 * s2,             s4 = 2.f * c2 * s2;
    float c8 = c4 * c4 - s4 * s4,             s8 = 2.f * c4 * s4;
    float c12 = c8 * c4 - s8 * s4,            s12 = c8 * s4 + s8 * c4;
    float C0 = rowC0[i], C1 = rowC1[i];
    float cr0 = C0 * c12 - C1 * s12;
    float cr1 = C0 * s12 + C1 * c12;
    float2 hv = HS[cur][(3 * bh + dy + 1) * 51 + (3 * bw + dx + 1)];
    outRow0[i] = cr0 * hv.x;
    outRow1[i] = cr1 * hv.y;
  }
}

// ---------------------------------------------------------------------------
// transpose: HgF [k][p] f32 -> Hbf [p][k] plain bf16 (64x64 LDS tiles).
// ---------------------------------------------------------------------------
__global__ __launch_bounds__(256) void transpose_cvt(
    const float* __restrict__ HgF, ushort_t* __restrict__ Hbf) {
  __shared__ float T[64][65];
  const int tid = threadIdx.x;
  const int p0 = blockIdx.x * 64;
  const int k0 = blockIdx.y * 64;
  {
    int row = tid >> 2, q = tid & 3;
    const float* src = &HgF[(size_t)(k0 + row) * PTOT + p0 + q * 16];
#pragma unroll
    for (int v = 0; v < 4; ++v) {
      float4 f = *(const float4*)(src + 4 * v);
      T[row][q * 16 + 4 * v + 0] = f.x;
      T[row][q * 16 + 4 * v + 1] = f.y;
      T[row][q * 16 + 4 * v + 2] = f.z;
      T[row][q * 16 + 4 * v + 3] = f.w;
    }
  }
  __syncthreads();
  {
    int pr = tid >> 2, kq = tid & 3;
    uint_t Hw[8];
#pragma unroll
    for (int q = 0; q < 8; ++q)
      Hw[q] = cvt2_hi(T[kq * 16 + 2 * q][pr], T[kq * 16 + 2 * q + 1][pr]);
    size_t off = (size_t)(p0 + pr) * 256 + k0 + kq * 16;
    *(uint4*)&Hbf[off]     = make_uint4(Hw[0], Hw[1], Hw[2], Hw[3]);
    *(uint4*)&Hbf[off + 8] = make_uint4(Hw[4], Hw[5], Hw[6], Hw[7]);
  }
}

// ---------------------------------------------------------------------------
// GEMM C: glds + T4 async pipeline (3 buffers, 2-deep, vmcnt(4)).
// ---------------------------------------------------------------------------
__global__ __launch_bounds__(256) void gemm_out_glds(
    const ushort_t* __restrict__ Hbf, const ushort_t* __restrict__ WoT,
    const float* __restrict__ b_out, float* __restrict__ out) {
  __shared__ ushort_t As[3][4096];   // Hg tiles
  __shared__ ushort_t Bs[3][4096];   // W_out^T tiles
  const int tid = threadIdx.x;
  const int lane = tid & 63, wv = tid >> 6;
  const int wr = wv >> 1, wc = wv & 1;
  const int lk = lane >> 4, lm = lane & 15;
  int lin = blockIdx.x;                    // 0..1727, 1728 = 8*216
  int id2 = (lin & 7) * 216 + (lin >> 3);
  const int jblk = id2 % 6, pblk = id2 / 6;
  const int j0 = jblk * 128, p0 = pblk * 128;

  f32x4 acc[4][4];
#pragma unroll
  for (int i = 0; i < 4; ++i)
#pragma unroll
    for (int j = 0; j < 4; ++j) acc[i][j] = (f32x4)0.f;

  auto stage = [&](int buf, int kidx) {
    const int k0 = kidx * 32;
#pragma unroll
    for (int j = 0; j < 2; ++j) {
      int mb = __builtin_amdgcn_readfirstlane(wv * 128 + j * 64);
      int m = mb + lane;
      int row = m >> 2, sp = m & 3;
      int g = sp ^ ((row >> 1) & 3);
      glds16(&Hbf[(size_t)(p0 + row) * 256 + k0 + g * 8],
             (void*)&As[buf][mb * 8]);
    }
#pragma unroll
    for (int j = 0; j < 2; ++j) {
      int mb = __builtin_amdgcn_readfirstlane(wv * 128 + j * 64);
      int m = mb + lane;
      int row = m >> 2, sp = m & 3;
      int g = sp ^ ((row >> 1) & 3);
      glds16(&WoT[(size_t)(j0 + row) * 256 + k0 + g * 8],
             (void*)&Bs[buf][mb * 8]);
    }
  };

  stage(0, 0);
  stage(1, 1);

  for (int kidx = 0; kidx < 8; ++kidx) {
    const int cur = kidx % 3;
    if (kidx < 7) { VM_WAIT(4); } else { VM_WAIT(0); }
    __builtin_amdgcn_s_barrier();
    __builtin_amdgcn_sched_barrier(0);
    int nk = kidx + 2;
    if (nk < 8) stage(nk % 3, nk);

    bfx8 ah[4], bh[4];
#pragma unroll
    for (int f = 0; f < 4; ++f) {
      int ra = wr * 64 + f * 16 + lm;
      int sa = lk ^ ((ra >> 1) & 3);
      ah[f] = *(const bfx8*)&As[cur][(ra * 4 + sa) * 8];
      int rb = wc * 64 + f * 16 + lm;
      int sb2 = lk ^ ((rb >> 1) & 3);
      bh[f] = *(const bfx8*)&Bs[cur][(rb * 4 + sb2) * 8];
    }
#pragma unroll
    for (int i = 0; i < 4; ++i)
#pragma unroll
      for (int j = 0; j < 4; ++j)
        acc[i][j] = MFMA_BF16(ah[i], bh[j], acc[i][j]);
  }

  float bo[4];
#pragma unroll
  for (int jj = 0; jj < 4; ++jj) bo[jj] = b_out[j0 + wc * 64 + jj * 16 + lm];
#pragma unroll
  for (int i = 0; i < 4; ++i) {
#pragma unroll
    for (int r = 0; r < 4; ++r) {
      int p = p0 + wr * 64 + i * 16 + lk * 4 + r;
      size_t rowoff = (size_t)p * DIM;
#pragma unroll
      for (int jj = 0; jj < 4; ++jj) {
        out[rowoff + j0 + wc * 64 + jj * 16 + lm] =
            siluf_(acc[i][jj][r] + bo[jj]);
      }
    }
  }
}

// ---------------------------------------------------------------------------
extern "C" void kernel_launch(void* const* d_in, const int* in_sizes, int n_in,
                              void* d_out, int out_size, void* d_ws, size_t ws_size,
                              hipStream_t stream) {
  const float* x      = (const float*)d_in[0];
  const float* W_B    = (const float*)d_in[1];
  const float* b_B    = (const float*)d_in[2];
  const float* W_C    = (const float*)d_in[3];
  const float* b_C    = (const float*)d_in[4];
  const float* W_X    = (const float*)d_in[5];
  const float* b_X    = (const float*)d_in[6];
  const float* W_dec  = (const float*)d_in[7];
  const float* b_dec  = (const float*)d_in[8];
  const float* W_th   = (const float*)d_in[9];
  const float* b_th   = (const float*)d_in[10];
  const float* W_lam  = (const float*)d_in[11];
  const float* b_lam  = (const float*)d_in[12];
  const float* B_bias = (const float*)d_in[13];
  const float* C_bias = (const float*)d_in[14];
  const float* conv_w = (const float*)d_in[15];
  const float* conv_b = (const float*)d_in[16];
  const float* W_out  = (const float*)d_in[17];
  const float* b_out  = (const float*)d_in[18];
  float* out = (float*)d_out;

  // workspace layout (~131 MB, round-4 proven):
  //  [weights ~2.4 MB][projT 90.8 MB][HgF 37.75 MB]
  //  Hbf (18.9 MB) OVERLAYS projT (dead after iter_kernel).
  ushort_t* WhiT  = (ushort_t*)d_ws;                      // 640*768
  ushort_t* WloT  = WhiT + (size_t)NCOLS * DIM;
  ushort_t* WoT   = WloT + (size_t)NCOLS * DIM;           // 768*256
  float* bias_all = (float*)(WoT + (size_t)DIM * 256);    // 640
  float* projT    = bias_all + NCOLS;                     // 616*36864 f32
  float* HgF      = projT + (size_t)PROJ_ROWS * PTOT;     // 256*36864 f32
  ushort_t* Hbf   = (ushort_t*)projT;                     // overlay

  const int pack_elems = NCOLS * DIM + DIM * 256;
  pack_kernel<<<(pack_elems + 255) / 256, 256, 0, stream>>>(
      W_B, W_C, W_dec, W_th, W_X, W_lam,
      b_B, b_C, b_dec, b_th, b_X, b_lam, B_bias, C_bias, W_out,
      WhiT, WloT, WoT, bias_all);

  gemm_proj_glds<0><<<dim3(4 * NPBLK), 256, 0, stream>>>(
      x, WhiT, WloT, bias_all, projT);
  gemm_proj_glds<1><<<dim3(NPBLK), 256, 0, stream>>>(
      x, WhiT, WloT, bias_all, projT);

  iter_kernel<<<dim3(32, 4, 16), 256, 0, stream>>>(
      projT, conv_w, conv_b, HgF);

  transpose_cvt<<<dim3(PTOT / 64, 4), 256, 0, stream>>>(HgF, Hbf);

  gemm_out_glds<<<dim3(6 * NPBLK), 256, 0, stream>>>(
      Hbf, WoT, b_out, out);
}

// Round 11
// 276.086 us; speedup vs baseline: 1.1496x; 1.1496x over previous
//
#include <hip/hip_runtime.h>
#include <hip/hip_bf16.h>
#include <math.h>

// Problem constants
#define PTOT 36864          // Bsz*Hs*Ws = 16*48*48
#define DIM 768
#define NCOLS 640           // packed projection columns (613 used, padded)
#define IMG 2304            // 48*48
#define KSTEPS 24           // 768/32
#define NPBLK 288           // PTOT/128

typedef unsigned short ushort_t;
typedef unsigned int uint_t;
typedef __attribute__((ext_vector_type(8))) short bfx8;
typedef __attribute__((ext_vector_type(4))) float f32x4;

#define MFMA_BF16(a, b, c) __builtin_amdgcn_mfma_f32_16x16x32_bf16((a), (b), (c), 0, 0, 0)

__device__ __forceinline__ float sigmoidf_(float v) { return 1.f / (1.f + __expf(-v)); }
__device__ __forceinline__ float siluf_(float v)    { return v   / (1.f + __expf(-v)); }
__device__ __forceinline__ float rfl(float v) {
  return __int_as_float(__builtin_amdgcn_readfirstlane(__float_as_int(v)));
}
__device__ __forceinline__ float bf2f(ushort_t h) {
  return __uint_as_float(((uint_t)h) << 16);
}

// async global->LDS, 16B per lane; LDS dest = wave-uniform base + lane*16
typedef __attribute__((address_space(3))) unsigned int lds_uint;
typedef __attribute__((address_space(1))) const unsigned int g_uint;
__device__ __forceinline__ void glds16(const void* gsrc, void* ldst) {
  __builtin_amdgcn_global_load_lds((g_uint*)gsrc, (lds_uint*)ldst, 16, 0, 0);
}

// split a pair of f32 into packed bf16 hi word + bf16 lo word (cvt_pk-based)
__device__ __forceinline__ void split2(float a, float b, uint_t& hw, uint_t& lw) {
  __hip_bfloat162 hh = __float22bfloat162_rn(make_float2(a, b));
  uint_t hu; __builtin_memcpy(&hu, &hh, 4);
  float ha = __uint_as_float(hu << 16);
  float hb = __uint_as_float(hu & 0xffff0000u);
  __hip_bfloat162 ll = __float22bfloat162_rn(make_float2(a - ha, b - hb));
  uint_t lu; __builtin_memcpy(&lu, &ll, 4);
  hw = hu; lw = lu;
}
__device__ __forceinline__ uint_t cvt2_hi(float a, float b) {
  __hip_bfloat162 hh = __float22bfloat162_rn(make_float2(a, b));
  uint_t hu; __builtin_memcpy(&hu, &hh, 4);
  return hu;
}
__device__ __forceinline__ ushort_t f2bf(float a) {
  return (ushort_t)(cvt2_hi(a, 0.f) & 0xffffu);
}
__device__ __forceinline__ void split8_fast(const float* f, uint4& hi, uint4& lo) {
  uint_t* Hp = (uint_t*)&hi;
  uint_t* Lp = (uint_t*)&lo;
#pragma unroll
  for (int q = 0; q < 4; ++q) split2(f[2 * q], f[2 * q + 1], Hp[q], Lp[q]);
}
__device__ __forceinline__ void cvt8_hi(const float* f, uint4& hi) {
  uint_t* Hp = (uint_t*)&hi;
#pragma unroll
  for (int q = 0; q < 4; ++q) Hp[q] = cvt2_hi(f[2 * q], f[2 * q + 1]);
}

// ---------------------------------------------------------------------------
// pack: projection weights -> split-bf16 [c][k]; W_out^T -> plain bf16 [j][k];
// fused bias.
// ---------------------------------------------------------------------------
__global__ void pack_kernel(
    const float* __restrict__ W_B, const float* __restrict__ W_C,
    const float* __restrict__ W_dec, const float* __restrict__ W_th,
    const float* __restrict__ W_X, const float* __restrict__ W_lam,
    const float* __restrict__ b_B, const float* __restrict__ b_C,
    const float* __restrict__ b_dec, const float* __restrict__ b_th,
    const float* __restrict__ b_X, const float* __restrict__ b_lam,
    const float* __restrict__ B_bias, const float* __restrict__ C_bias,
    const float* __restrict__ W_out,
    ushort_t* __restrict__ WhiT, ushort_t* __restrict__ WloT,
    ushort_t* __restrict__ WoT, float* __restrict__ bias_all) {
  int idx = blockIdx.x * 256 + threadIdx.x;
  const int NW = NCOLS * DIM;          // 491520
  const int NWO = DIM * 256;           // 196608
  if (idx < NW) {
    int c = idx / DIM, k = idx - c * DIM;
    float v;
    if      (c < 256) v = W_B[k * 256 + c];
    else if (c < 512) v = W_C[k * 256 + (c - 256)];
    else if (c < 576) v = W_dec[k * 64 + (c - 512)];
    else if (c < 608) v = W_th[k * 32 + (c - 576)];
    else if (c < 612) v = W_X[k * 4 + (c - 608)];
    else if (c == 612) v = W_lam[k];
    else v = 0.f;
    uint_t hw, lw;
    split2(v, 0.f, hw, lw);
    WhiT[idx] = (ushort_t)(hw & 0xffffu);
    WloT[idx] = (ushort_t)(lw & 0xffffu);
  } else if (idx < NW + NWO) {
    int t = idx - NW;
    int j = t / 256, k = t - j * 256;
    WoT[t] = f2bf(W_out[k * DIM + j]);
  }
  if (idx < NCOLS) {
    int c = idx;
    float v;
    if      (c < 256) v = b_B[c] + B_bias[c];
    else if (c < 512) v = b_C[c - 256] + C_bias[c - 256];
    else if (c < 576) v = b_dec[c - 512];
    else if (c < 608) v = b_th[c - 576];
    else if (c < 612) v = b_X[c - 608];
    else if (c == 612) v = b_lam[0];
    else v = 0.f;
    bias_all[c] = v;
  }
}

// ---------------------------------------------------------------------------
// GEMM A: round-9 proven structure (glds, row-major+XOR maps, 2-buffer,
// __syncthreads). Output precision split:
//   HEAVY=0 (c 0-511, B/C): plain bf16 MFMA, output BF16 -> projBC (halves
//           the dominant write traffic; silu outputs tolerate bf16).
//   HEAVY=1 (c 512-612): split-bf16 MFMA, output F32 -> projS rows c-512
//           (theta must stay f32: x12 angle amplification in rope).
// ---------------------------------------------------------------------------
template <int HEAVY>
__global__ __launch_bounds__(256) void gemm_proj_glds(
    const float* __restrict__ x, const ushort_t* __restrict__ WhiT,
    const ushort_t* __restrict__ WloT, const float* __restrict__ biasall,
    ushort_t* __restrict__ projBC, float* __restrict__ projS) {
  __shared__ ushort_t Ash[2][4096];                       // W hi tiles
  __shared__ ushort_t Asl[HEAVY ? 2 : 1][HEAVY ? 4096 : 4];
  __shared__ float    Bsf[2][4096];                       // x f32 tiles
  const int tid = threadIdx.x;
  const int lane = tid & 63, wv = tid >> 6;
  const int wr = wv >> 1, wc = wv & 1;
  const int lk = lane >> 4, lm = lane & 15;

  int cblk, pblk;
  if (HEAVY) {
    int lin = blockIdx.x;                  // 0..287, 288 = 8*36
    int id2 = (lin & 7) * 36 + (lin >> 3);
    cblk = 4; pblk = id2;
  } else {
    int lin = blockIdx.x;                  // 0..1151, 1152 = 8*144
    int id2 = (lin & 7) * 144 + (lin >> 3);
    cblk = id2 & 3; pblk = id2 >> 2;       // cblk fastest -> x L2 reuse per XCD
  }
  const int c0 = cblk * 128, p0 = pblk * 128;

  f32x4 acc[4][4];
#pragma unroll
  for (int i = 0; i < 4; ++i)
#pragma unroll
    for (int j = 0; j < 4; ++j) acc[i][j] = (f32x4)0.f;

  auto stage = [&](int buf, int kidx) {
    const int k0 = kidx * 32;
    // W hi: 512 chunks, m = row*4 + sp; 4 lanes cover one 64B row
#pragma unroll
    for (int j = 0; j < 2; ++j) {
      int mb = __builtin_amdgcn_readfirstlane(wv * 128 + j * 64);
      int m = mb + lane;
      int row = m >> 2, sp = m & 3;
      int g = sp ^ ((row >> 1) & 3);
      glds16(&WhiT[(size_t)(c0 + row) * DIM + k0 + g * 8],
             (void*)&Ash[buf][mb * 8]);
    }
    if (HEAVY) {
#pragma unroll
      for (int j = 0; j < 2; ++j) {
        int mb = __builtin_amdgcn_readfirstlane(wv * 128 + j * 64);
        int m = mb + lane;
        int row = m >> 2, sp = m & 3;
        int g = sp ^ ((row >> 1) & 3);
        glds16(&WloT[(size_t)(c0 + row) * DIM + k0 + g * 8],
               (void*)&Asl[buf][mb * 8]);
      }
    }
    // x f32: 1024 chunks, m = row*8 + sp; 8 lanes cover one 128B row
#pragma unroll
    for (int j = 0; j < 4; ++j) {
      int mb = __builtin_amdgcn_readfirstlane(wv * 256 + j * 64);
      int m = mb + lane;
      int row = m >> 3, sp = m & 7;
      int g = sp ^ (row & 7);
      glds16(&x[(size_t)(p0 + row) * DIM + k0 + g * 4],
             (void*)&Bsf[buf][mb * 4]);
    }
  };

  stage(0, 0);
  __syncthreads();

  for (int kidx = 0; kidx < KSTEPS; ++kidx) {
    const int cur = kidx & 1;
    if (kidx + 1 < KSTEPS) stage(cur ^ 1, kidx + 1);

    bfx8 ah[4], al[4];
#pragma unroll
    for (int f = 0; f < 4; ++f) {
      int row = wr * 64 + f * 16 + lm;
      int sp = lk ^ ((row >> 1) & 3);
      int idx = (row * 4 + sp) * 8;
      ah[f] = *(const bfx8*)&Ash[cur][idx];
      if (HEAVY) al[f] = *(const bfx8*)&Asl[cur][idx];
    }
    bfx8 bh[4], bl[4];
#pragma unroll
    for (int f = 0; f < 4; ++f) {
      int row = wc * 64 + f * 16 + lm;
      int sp0 = (2 * lk)     ^ (row & 7);
      int sp1 = (2 * lk + 1) ^ (row & 7);
      float fv[8];
      *(float4*)&fv[0] = *(const float4*)&Bsf[cur][(row * 8 + sp0) * 4];
      *(float4*)&fv[4] = *(const float4*)&Bsf[cur][(row * 8 + sp1) * 4];
      if (HEAVY) {
        uint4 hv, lv;
        split8_fast(fv, hv, lv);
        bh[f] = *(bfx8*)&hv;
        bl[f] = *(bfx8*)&lv;
      } else {
        uint4 hv;
        cvt8_hi(fv, hv);
        bh[f] = *(bfx8*)&hv;
      }
    }
#pragma unroll
    for (int i = 0; i < 4; ++i)
#pragma unroll
      for (int j = 0; j < 4; ++j) {
        acc[i][j] = MFMA_BF16(ah[i], bh[j], acc[i][j]);
        if (HEAVY) {
          acc[i][j] = MFMA_BF16(al[i], bh[j], acc[i][j]);
          acc[i][j] = MFMA_BF16(ah[i], bl[j], acc[i][j]);
        }
      }
    __syncthreads();
  }

#pragma unroll
  for (int i = 0; i < 4; ++i) {
#pragma unroll
    for (int r = 0; r < 4; ++r) {
      int c = c0 + wr * 64 + i * 16 + lk * 4 + r;
      float bia = biasall[c];
      if (HEAVY) {
        if (c >= 613) continue;
        int rowo = c - 512;
        bool do_silu = (c >= 608 && c < 612);
        bool do_sig  = (c < 576) || (c == 612);
#pragma unroll
        for (int j = 0; j < 4; ++j) {
          float z = acc[i][j][r] + bia;
          if (do_silu) z = siluf_(z);
          else if (do_sig) z = sigmoidf_(z);
          projS[(size_t)rowo * PTOT + p0 + wc * 64 + j * 16 + lm] = z;
        }
      } else {
#pragma unroll
        for (int j = 0; j < 4; ++j) {
          float z = siluf_(acc[i][j][r] + bia);
          projBC[(size_t)c * PTOT + p0 + wc * 64 + j * 16 + lm] = f2bf(z);
        }
      }
    }
  }
}

// ---------------------------------------------------------------------------
// Iteration kernel: one block per (n-pair, r, batch), 12 iterations fused.
// Reads B/C as bf16 (projBC) and alpha/theta/X/gamma as f32 (projS).
// Emits Hg directly as BF16 in [k][p] layout (same rounding the transpose
// applied before -> numerically identical, half the bytes).
// ---------------------------------------------------------------------------
__global__ __launch_bounds__(256) void iter_kernel(
    const ushort_t* __restrict__ projBC, const float* __restrict__ projS,
    const float* __restrict__ conv_w, const float* __restrict__ conv_b,
    ushort_t* __restrict__ HgBf) {
  const int n2 = blockIdx.x;   // channel pair 0..31
  const int r  = blockIdx.y;   // 0..3
  const int b  = blockIdx.z;   // 0..15
  const int n0 = 2 * n2, n1 = n0 + 1;
  const int tid = threadIdx.x;
  const int bh = tid >> 4, bw = tid & 15;   // 3x3 strip coords
  const int pbase = b * IMG;

  __shared__ float2 HS[2][50 * 51];   // [buf][(h+1)*51 + (w+1)], zero halo

  float w0[9], w1[9];
#pragma unroll
  for (int t = 0; t < 9; ++t) {
    w0[t] = rfl(conv_w[t * 64 + n0]);
    w1[t] = rfl(conv_w[t * 64 + n1]);
  }
  const float cvb0 = rfl(conv_b[n0]), cvb1 = rfl(conv_b[n1]);

  {
    float4 zz = {0.f, 0.f, 0.f, 0.f};
    float4* z = (float4*)&HS[0][0];
#pragma unroll
    for (int u = 0; u < 10; ++u) {
      int q = tid + 256 * u;
      if (q < 2550) z[q] = zz;
    }
  }

  const ushort_t* rowB0 = projBC + (size_t)(n0 * 4 + r) * PTOT + pbase;
  const ushort_t* rowB1 = projBC + (size_t)(n1 * 4 + r) * PTOT + pbase;
  const ushort_t* rowC0 = projBC + (size_t)(256 + n0 * 4 + r) * PTOT + pbase;
  const ushort_t* rowC1 = projBC + (size_t)(256 + n1 * 4 + r) * PTOT + pbase;
  const float* rowA0 = projS + (size_t)n0 * PTOT + pbase;          // alpha
  const float* rowA1 = projS + (size_t)n1 * PTOT + pbase;
  const float* rowTh = projS + (size_t)(64 + n2) * PTOT + pbase;   // theta
  const float* rowXv = projS + (size_t)(96 + r) * PTOT + pbase;    // X
  const float* rowGm = projS + (size_t)100 * PTOT + pbase;         // gamma

  float be0[9], be1[9], cb[9], sb[9], al0[9], al1[9], gmv[9];
#pragma unroll
  for (int s = 0; s < 9; ++s) {
    int dy = s / 3, dx = s - 3 * dy;
    int i = (3 * bh + dy) * 48 + 3 * bw + dx;
    float sn, cn;
    __sincosf(rowTh[i], &sn, &cn);
    cb[s] = cn; sb[s] = sn;
    float B0 = bf2f(rowB0[i]), B1 = bf2f(rowB1[i]), X = rowXv[i];
    be0[s] = (B0 * cn - B1 * sn) * X;   // inj at angle theta (iteration 0)
    be1[s] = (B0 * sn + B1 * cn) * X;
    al0[s] = rowA0[i]; al1[s] = rowA1[i];
    gmv[s] = rowGm[i];
  }
  __syncthreads();

  int cur = 0;
  for (int it = 0; it < 12; ++it) {
    float a0[9], a1[9];
#pragma unroll
    for (int s = 0; s < 9; ++s) { a0[s] = cvb0; a1[s] = cvb1; }
#pragma unroll
    for (int yy = 0; yy < 5; ++yy) {
      float2 row[5];
#pragma unroll
      for (int xx = 0; xx < 5; ++xx)
        row[xx] = HS[cur][(3 * bh + yy) * 51 + 3 * bw + xx];
#pragma unroll
      for (int dy = 0; dy < 3; ++dy) {
        int ty = yy - dy;
        if (ty < 0 || ty > 2) continue;
#pragma unroll
        for (int dx = 0; dx < 3; ++dx)
#pragma unroll
          for (int tx = 0; tx < 3; ++tx) {
            a0[dy * 3 + dx] += row[dx + tx].x * w0[ty * 3 + tx];
            a1[dy * 3 + dx] += row[dx + tx].y * w1[ty * 3 + tx];
          }
      }
    }
#pragma unroll
    for (int s = 0; s < 9; ++s) {
      int dy = s / 3, dx = s - 3 * dy;
      float h0, h1;
      if (it == 0) {
        h0 = al0[s] * a0[s] + be0[s];
        h1 = al1[s] * a1[s] + be1[s];
      } else {
        float p0 = be0[s] * cb[s] + be1[s] * sb[s];
        float p1 = be1[s] * cb[s] - be0[s] * sb[s];
        float g = gmv[s];
        h0 = al0[s] * (a0[s] + (1.f - g) * p0) + g * be0[s];
        h1 = al1[s] * (a1[s] + (1.f - g) * p1) + g * be1[s];
      }
      float2 hw; hw.x = h0; hw.y = h1;
      HS[cur ^ 1][(3 * bh + dy + 1) * 51 + (3 * bw + dx + 1)] = hw;
      if (it < 11) {
        float nb0 = be0[s] * cb[s] - be1[s] * sb[s];
        float nb1 = be0[s] * sb[s] + be1[s] * cb[s];
        be0[s] = nb0; be1[s] = nb1;
      }
    }
    __syncthreads();
    cur ^= 1;
  }

  ushort_t* outRow0 = HgBf + (size_t)(r * 64 + n0) * PTOT + pbase;
  ushort_t* outRow1 = HgBf + (size_t)(r * 64 + n1) * PTOT + pbase;
#pragma unroll
  for (int s = 0; s < 9; ++s) {
    int dy = s / 3, dx = s - 3 * dy;
    int i = (3 * bh + dy) * 48 + 3 * bw + dx;
    float c2 = cb[s] * cb[s] - sb[s] * sb[s], s2 = 2.f * cb[s] * sb[s];
    float c4 = c2 * c2 - s2 * s2,             s4 = 2.f * c2 * s2;
    float c8 = c4 * c4 - s4 * s4,             s8 = 2.f * c4 * s4;
    float c12 = c8 * c4 - s8 * s4,            s12 = c8 * s4 + s8 * c4;
    float C0 = bf2f(rowC0[i]), C1 = bf2f(rowC1[i]);
    float cr0 = C0 * c12 - C1 * s12;
    float cr1 = C0 * s12 + C1 * c12;
    float2 hv = HS[cur][(3 * bh + dy + 1) * 51 + (3 * bw + dx + 1)];
    outRow0[i] = f2bf(cr0 * hv.x);
    outRow1[i] = f2bf(cr1 * hv.y);
  }
}

// ---------------------------------------------------------------------------
// transpose: HgBf [k][p] bf16 -> Hbf [p][k] bf16 (f32 64x65 LDS tile, proven
// bank layout; conversion bf16->f32 on write, f32->bf16 pack on read).
// ---------------------------------------------------------------------------
__global__ __launch_bounds__(256) void transpose_cvt(
    const ushort_t* __restrict__ HgBf, ushort_t* __restrict__ Hbf) {
  __shared__ float T[64][65];
  const int tid = threadIdx.x;
  const int p0 = blockIdx.x * 64;
  const int k0 = blockIdx.y * 64;
  {
    int row = tid >> 2, q = tid & 3;
    const ushort_t* src = &HgBf[(size_t)(k0 + row) * PTOT + p0 + q * 16];
    uint4 u0 = *(const uint4*)src;
    uint4 u1 = *(const uint4*)(src + 8);
    const uint_t* up = (const uint_t*)&u0;
#pragma unroll
    for (int t = 0; t < 4; ++t) {
      T[row][q * 16 + 2 * t]     = bf2f((ushort_t)(up[t] & 0xffffu));
      T[row][q * 16 + 2 * t + 1] = bf2f((ushort_t)(up[t] >> 16));
    }
    const uint_t* vp = (const uint_t*)&u1;
#pragma unroll
    for (int t = 0; t < 4; ++t) {
      T[row][q * 16 + 8 + 2 * t]     = bf2f((ushort_t)(vp[t] & 0xffffu));
      T[row][q * 16 + 8 + 2 * t + 1] = bf2f((ushort_t)(vp[t] >> 16));
    }
  }
  __syncthreads();
  {
    int pr = tid >> 2, kq = tid & 3;
    uint_t Hw[8];
#pragma unroll
    for (int q = 0; q < 8; ++q)
      Hw[q] = cvt2_hi(T[kq * 16 + 2 * q][pr], T[kq * 16 + 2 * q + 1][pr]);
    size_t off = (size_t)(p0 + pr) * 256 + k0 + kq * 16;
    *(uint4*)&Hbf[off]     = make_uint4(Hw[0], Hw[1], Hw[2], Hw[3]);
    *(uint4*)&Hbf[off + 8] = make_uint4(Hw[4], Hw[5], Hw[6], Hw[7]);
  }
}

// ---------------------------------------------------------------------------
// GEMM C: round-9 structure (glds, 2-buffer, __syncthreads, XOR maps).
// ---------------------------------------------------------------------------
__global__ __launch_bounds__(256) void gemm_out_glds(
    const ushort_t* __restrict__ Hbf, const ushort_t* __restrict__ WoT,
    const float* __restrict__ b_out, float* __restrict__ out) {
  __shared__ ushort_t As[2][4096];   // Hg tiles
  __shared__ ushort_t Bs[2][4096];   // W_out^T tiles
  const int tid = threadIdx.x;
  const int lane = tid & 63, wv = tid >> 6;
  const int wr = wv >> 1, wc = wv & 1;
  const int lk = lane >> 4, lm = lane & 15;
  int lin = blockIdx.x;                    // 0..1727, 1728 = 8*216
  int id2 = (lin & 7) * 216 + (lin >> 3);
  const int jblk = id2 % 6, pblk = id2 / 6;
  const int j0 = jblk * 128, p0 = pblk * 128;

  f32x4 acc[4][4];
#pragma unroll
  for (int i = 0; i < 4; ++i)
#pragma unroll
    for (int j = 0; j < 4; ++j) acc[i][j] = (f32x4)0.f;

  auto stage = [&](int buf, int kidx) {
    const int k0 = kidx * 32;
#pragma unroll
    for (int j = 0; j < 2; ++j) {
      int mb = __builtin_amdgcn_readfirstlane(wv * 128 + j * 64);
      int m = mb + lane;
      int row = m >> 2, sp = m & 3;
      int g = sp ^ ((row >> 1) & 3);
      glds16(&Hbf[(size_t)(p0 + row) * 256 + k0 + g * 8],
             (void*)&As[buf][mb * 8]);
    }
#pragma unroll
    for (int j = 0; j < 2; ++j) {
      int mb = __builtin_amdgcn_readfirstlane(wv * 128 + j * 64);
      int m = mb + lane;
      int row = m >> 2, sp = m & 3;
      int g = sp ^ ((row >> 1) & 3);
      glds16(&WoT[(size_t)(j0 + row) * 256 + k0 + g * 8],
             (void*)&Bs[buf][mb * 8]);
    }
  };

  stage(0, 0);
  __syncthreads();

  for (int kidx = 0; kidx < 8; ++kidx) {
    const int cur = kidx & 1;
    if (kidx + 1 < 8) stage(cur ^ 1, kidx + 1);
    bfx8 ah[4], bh[4];
#pragma unroll
    for (int f = 0; f < 4; ++f) {
      int ra = wr * 64 + f * 16 + lm;
      int sa = lk ^ ((ra >> 1) & 3);
      ah[f] = *(const bfx8*)&As[cur][(ra * 4 + sa) * 8];
      int rb = wc * 64 + f * 16 + lm;
      int sb2 = lk ^ ((rb >> 1) & 3);
      bh[f] = *(const bfx8*)&Bs[cur][(rb * 4 + sb2) * 8];
    }
#pragma unroll
    for (int i = 0; i < 4; ++i)
#pragma unroll
      for (int j = 0; j < 4; ++j)
        acc[i][j] = MFMA_BF16(ah[i], bh[j], acc[i][j]);
    __syncthreads();
  }

  float bo[4];
#pragma unroll
  for (int jj = 0; jj < 4; ++jj) bo[jj] = b_out[j0 + wc * 64 + jj * 16 + lm];
#pragma unroll
  for (int i = 0; i < 4; ++i) {
#pragma unroll
    for (int r = 0; r < 4; ++r) {
      int p = p0 + wr * 64 + i * 16 + lk * 4 + r;
      size_t rowoff = (size_t)p * DIM;
#pragma unroll
      for (int jj = 0; jj < 4; ++jj) {
        out[rowoff + j0 + wc * 64 + jj * 16 + lm] =
            siluf_(acc[i][jj][r] + bo[jj]);
      }
    }
  }
}

// ---------------------------------------------------------------------------
extern "C" void kernel_launch(void* const* d_in, const int* in_sizes, int n_in,
                              void* d_out, int out_size, void* d_ws, size_t ws_size,
                              hipStream_t stream) {
  const float* x      = (const float*)d_in[0];
  const float* W_B    = (const float*)d_in[1];
  const float* b_B    = (const float*)d_in[2];
  const float* W_C    = (const float*)d_in[3];
  const float* b_C    = (const float*)d_in[4];
  const float* W_X    = (const float*)d_in[5];
  const float* b_X    = (const float*)d_in[6];
  const float* W_dec  = (const float*)d_in[7];
  const float* b_dec  = (const float*)d_in[8];
  const float* W_th   = (const float*)d_in[9];
  const float* b_th   = (const float*)d_in[10];
  const float* W_lam  = (const float*)d_in[11];
  const float* b_lam  = (const float*)d_in[12];
  const float* B_bias = (const float*)d_in[13];
  const float* C_bias = (const float*)d_in[14];
  const float* conv_w = (const float*)d_in[15];
  const float* conv_b = (const float*)d_in[16];
  const float* W_out  = (const float*)d_in[17];
  const float* b_out  = (const float*)d_in[18];
  float* out = (float*)d_out;

  // workspace layout (~93 MB, under proven 131 MB):
  //  weights 2.4 | projBC bf16 37.75 | projS f32 15.3 | HgBf 18.9 | Hbf 18.9
  ushort_t* WhiT   = (ushort_t*)d_ws;                     // 640*768
  ushort_t* WloT   = WhiT + (size_t)NCOLS * DIM;
  ushort_t* WoT    = WloT + (size_t)NCOLS * DIM;          // 768*256
  float* bias_all  = (float*)(WoT + (size_t)DIM * 256);   // 640
  ushort_t* projBC = (ushort_t*)(bias_all + NCOLS);       // 512*36864 bf16
  float* projS     = (float*)(projBC + (size_t)512 * PTOT);  // 104*36864 f32
  ushort_t* HgBf   = (ushort_t*)(projS + (size_t)104 * PTOT); // 256*36864 bf16
  ushort_t* Hbf    = HgBf + (size_t)256 * PTOT;           // 36864*256 bf16

  const int pack_elems = NCOLS * DIM + DIM * 256;
  pack_kernel<<<(pack_elems + 255) / 256, 256, 0, stream>>>(
      W_B, W_C, W_dec, W_th, W_X, W_lam,
      b_B, b_C, b_dec, b_th, b_X, b_lam, B_bias, C_bias, W_out,
      WhiT, WloT, WoT, bias_all);

  gemm_proj_glds<0><<<dim3(4 * NPBLK), 256, 0, stream>>>(
      x, WhiT, WloT, bias_all, projBC, projS);
  gemm_proj_glds<1><<<dim3(NPBLK), 256, 0, stream>>>(
      x, WhiT, WloT, bias_all, projBC, projS);

  iter_kernel<<<dim3(32, 4, 16), 256, 0, stream>>>(
      projBC, projS, conv_w, conv_b, HgBf);

  transpose_cvt<<<dim3(PTOT / 64, 4), 256, 0, stream>>>(HgBf, Hbf);

  gemm_out_glds<<<dim3(6 * NPBLK), 256, 0, stream>>>(
      Hbf, WoT, b_out, out);
}

// Round 12
// 243.059 us; speedup vs baseline: 1.3058x; 1.1359x over previous
//
#include <hip/hip_runtime.h>
#include <hip/hip_bf16.h>
#include <math.h>

// Problem constants
#define PTOT 36864          // Bsz*Hs*Ws = 16*48*48
#define DIM 768
#define NCOLS 640           // packed projection columns (613 used, padded)
#define IMG 2304            // 48*48
#define KSTEPS 24           // 768/32
#define NPBLK 288           // PTOT/128

typedef unsigned short ushort_t;
typedef unsigned int uint_t;
typedef __attribute__((ext_vector_type(8))) short bfx8;
typedef __attribute__((ext_vector_type(4))) float f32x4;

#define MFMA_BF16(a, b, c) __builtin_amdgcn_mfma_f32_16x16x32_bf16((a), (b), (c), 0, 0, 0)

__device__ __forceinline__ float sigmoidf_(float v) { return 1.f / (1.f + __expf(-v)); }
__device__ __forceinline__ float siluf_(float v)    { return v   / (1.f + __expf(-v)); }
__device__ __forceinline__ float rfl(float v) {
  return __int_as_float(__builtin_amdgcn_readfirstlane(__float_as_int(v)));
}
__device__ __forceinline__ float bf2f(ushort_t h) {
  return __uint_as_float(((uint_t)h) << 16);
}

// async global->LDS, 16B per lane; LDS dest = wave-uniform base + lane*16
typedef __attribute__((address_space(3))) unsigned int lds_uint;
typedef __attribute__((address_space(1))) const unsigned int g_uint;
__device__ __forceinline__ void glds16(const void* gsrc, void* ldst) {
  __builtin_amdgcn_global_load_lds((g_uint*)gsrc, (lds_uint*)ldst, 16, 0, 0);
}

// split a pair of f32 into packed bf16 hi word + bf16 lo word (cvt_pk-based)
__device__ __forceinline__ void split2(float a, float b, uint_t& hw, uint_t& lw) {
  __hip_bfloat162 hh = __float22bfloat162_rn(make_float2(a, b));
  uint_t hu; __builtin_memcpy(&hu, &hh, 4);
  float ha = __uint_as_float(hu << 16);
  float hb = __uint_as_float(hu & 0xffff0000u);
  __hip_bfloat162 ll = __float22bfloat162_rn(make_float2(a - ha, b - hb));
  uint_t lu; __builtin_memcpy(&lu, &ll, 4);
  hw = hu; lw = lu;
}
__device__ __forceinline__ uint_t cvt2_hi(float a, float b) {
  __hip_bfloat162 hh = __float22bfloat162_rn(make_float2(a, b));
  uint_t hu; __builtin_memcpy(&hu, &hh, 4);
  return hu;
}
__device__ __forceinline__ ushort_t f2bf(float a) {
  return (ushort_t)(cvt2_hi(a, 0.f) & 0xffffu);
}
__device__ __forceinline__ void split8_fast(const float* f, uint4& hi, uint4& lo) {
  uint_t* Hp = (uint_t*)&hi;
  uint_t* Lp = (uint_t*)&lo;
#pragma unroll
  for (int q = 0; q < 4; ++q) split2(f[2 * q], f[2 * q + 1], Hp[q], Lp[q]);
}
__device__ __forceinline__ void cvt8_hi(const float* f, uint4& hi) {
  uint_t* Hp = (uint_t*)&hi;
#pragma unroll
  for (int q = 0; q < 4; ++q) Hp[q] = cvt2_hi(f[2 * q], f[2 * q + 1]);
}

// ---------------------------------------------------------------------------
// pack: projection weights -> split-bf16 [c][k]; W_out^T -> plain bf16 [j][k];
// fused bias.
// ---------------------------------------------------------------------------
__global__ void pack_kernel(
    const float* __restrict__ W_B, const float* __restrict__ W_C,
    const float* __restrict__ W_dec, const float* __restrict__ W_th,
    const float* __restrict__ W_X, const float* __restrict__ W_lam,
    const float* __restrict__ b_B, const float* __restrict__ b_C,
    const float* __restrict__ b_dec, const float* __restrict__ b_th,
    const float* __restrict__ b_X, const float* __restrict__ b_lam,
    const float* __restrict__ B_bias, const float* __restrict__ C_bias,
    const float* __restrict__ W_out,
    ushort_t* __restrict__ WhiT, ushort_t* __restrict__ WloT,
    ushort_t* __restrict__ WoT, float* __restrict__ bias_all) {
  int idx = blockIdx.x * 256 + threadIdx.x;
  const int NW = NCOLS * DIM;          // 491520
  const int NWO = DIM * 256;           // 196608
  if (idx < NW) {
    int c = idx / DIM, k = idx - c * DIM;
    float v;
    if      (c < 256) v = W_B[k * 256 + c];
    else if (c < 512) v = W_C[k * 256 + (c - 256)];
    else if (c < 576) v = W_dec[k * 64 + (c - 512)];
    else if (c < 608) v = W_th[k * 32 + (c - 576)];
    else if (c < 612) v = W_X[k * 4 + (c - 608)];
    else if (c == 612) v = W_lam[k];
    else v = 0.f;
    uint_t hw, lw;
    split2(v, 0.f, hw, lw);
    WhiT[idx] = (ushort_t)(hw & 0xffffu);
    WloT[idx] = (ushort_t)(lw & 0xffffu);
  } else if (idx < NW + NWO) {
    int t = idx - NW;
    int j = t / 256, k = t - j * 256;
    WoT[t] = f2bf(W_out[k * DIM + j]);
  }
  if (idx < NCOLS) {
    int c = idx;
    float v;
    if      (c < 256) v = b_B[c] + B_bias[c];
    else if (c < 512) v = b_C[c - 256] + C_bias[c - 256];
    else if (c < 576) v = b_dec[c - 512];
    else if (c < 608) v = b_th[c - 576];
    else if (c < 612) v = b_X[c - 608];
    else if (c == 612) v = b_lam[0];
    else v = 0.f;
    bias_all[c] = v;
  }
}

// ---------------------------------------------------------------------------
// GEMM A: round-9 structure, 512 threads (8 waves of 64x32 sub-tiles) for
// 3 blocks/CU = 24 resident waves -> latency hiding of the barrier drain.
//   HEAVY=0 (c 0-511, B/C): plain bf16 MFMA, bf16 output -> projBC.
//   HEAVY=1 (c 512-612): split-bf16 MFMA, f32 output -> projS.
// ---------------------------------------------------------------------------
template <int HEAVY>
__global__ __launch_bounds__(512, HEAVY ? 4 : 6) void gemm_proj_glds(
    const float* __restrict__ x, const ushort_t* __restrict__ WhiT,
    const ushort_t* __restrict__ WloT, const float* __restrict__ biasall,
    ushort_t* __restrict__ projBC, float* __restrict__ projS) {
  __shared__ ushort_t Ash[2][4096];                       // W hi tiles
  __shared__ ushort_t Asl[HEAVY ? 2 : 1][HEAVY ? 4096 : 4];
  __shared__ float    Bsf[2][4096];                       // x f32 tiles
  const int tid = threadIdx.x;
  const int lane = tid & 63, wv = tid >> 6;   // wv 0..7
  const int wr = wv >> 2, wc = wv & 3;        // 2 x 4 waves of 64r x 32c
  const int lk = lane >> 4, lm = lane & 15;

  int cblk, pblk;
  if (HEAVY) {
    int lin = blockIdx.x;                  // 0..287, 288 = 8*36
    int id2 = (lin & 7) * 36 + (lin >> 3);
    cblk = 4; pblk = id2;
  } else {
    int lin = blockIdx.x;                  // 0..1151, 1152 = 8*144
    int id2 = (lin & 7) * 144 + (lin >> 3);
    cblk = id2 & 3; pblk = id2 >> 2;       // cblk fastest -> x L2 reuse per XCD
  }
  const int c0 = cblk * 128, p0 = pblk * 128;

  f32x4 acc[4][2];
#pragma unroll
  for (int i = 0; i < 4; ++i)
#pragma unroll
    for (int j = 0; j < 2; ++j) acc[i][j] = (f32x4)0.f;

  auto stage = [&](int buf, int kidx) {
    const int k0 = kidx * 32;
    // W hi: 512 chunks (one per thread), m = row*4 + sp
    {
      int mb = __builtin_amdgcn_readfirstlane(wv * 64);
      int m = mb + lane;
      int row = m >> 2, sp = m & 3;
      int g = sp ^ ((row >> 1) & 3);
      glds16(&WhiT[(size_t)(c0 + row) * DIM + k0 + g * 8],
             (void*)&Ash[buf][mb * 8]);
    }
    if (HEAVY) {
      int mb = __builtin_amdgcn_readfirstlane(wv * 64);
      int m = mb + lane;
      int row = m >> 2, sp = m & 3;
      int g = sp ^ ((row >> 1) & 3);
      glds16(&WloT[(size_t)(c0 + row) * DIM + k0 + g * 8],
             (void*)&Asl[buf][mb * 8]);
    }
    // x f32: 1024 chunks, m = row*8 + sp
#pragma unroll
    for (int j = 0; j < 2; ++j) {
      int mb = __builtin_amdgcn_readfirstlane(j * 512 + wv * 64);
      int m = mb + lane;
      int row = m >> 3, sp = m & 7;
      int g = sp ^ (row & 7);
      glds16(&x[(size_t)(p0 + row) * DIM + k0 + g * 4],
             (void*)&Bsf[buf][mb * 4]);
    }
  };

  stage(0, 0);
  __syncthreads();

  for (int kidx = 0; kidx < KSTEPS; ++kidx) {
    const int cur = kidx & 1;
    if (kidx + 1 < KSTEPS) stage(cur ^ 1, kidx + 1);

    bfx8 ah[4], al[4];
#pragma unroll
    for (int f = 0; f < 4; ++f) {
      int row = wr * 64 + f * 16 + lm;
      int sp = lk ^ ((row >> 1) & 3);
      int idx = (row * 4 + sp) * 8;
      ah[f] = *(const bfx8*)&Ash[cur][idx];
      if (HEAVY) al[f] = *(const bfx8*)&Asl[cur][idx];
    }
    bfx8 bh[2], bl[2];
#pragma unroll
    for (int n = 0; n < 2; ++n) {
      int row = wc * 32 + n * 16 + lm;
      int sp0 = (2 * lk)     ^ (row & 7);
      int sp1 = (2 * lk + 1) ^ (row & 7);
      float fv[8];
      *(float4*)&fv[0] = *(const float4*)&Bsf[cur][(row * 8 + sp0) * 4];
      *(float4*)&fv[4] = *(const float4*)&Bsf[cur][(row * 8 + sp1) * 4];
      if (HEAVY) {
        uint4 hv, lv;
        split8_fast(fv, hv, lv);
        bh[n] = *(bfx8*)&hv;
        bl[n] = *(bfx8*)&lv;
      } else {
        uint4 hv;
        cvt8_hi(fv, hv);
        bh[n] = *(bfx8*)&hv;
      }
    }
#pragma unroll
    for (int i = 0; i < 4; ++i)
#pragma unroll
      for (int j = 0; j < 2; ++j) {
        acc[i][j] = MFMA_BF16(ah[i], bh[j], acc[i][j]);
        if (HEAVY) {
          acc[i][j] = MFMA_BF16(al[i], bh[j], acc[i][j]);
          acc[i][j] = MFMA_BF16(ah[i], bl[j], acc[i][j]);
        }
      }
    __syncthreads();
  }

#pragma unroll
  for (int i = 0; i < 4; ++i) {
#pragma unroll
    for (int r = 0; r < 4; ++r) {
      int c = c0 + wr * 64 + i * 16 + lk * 4 + r;
      float bia = biasall[c];
      if (HEAVY) {
        if (c >= 613) continue;
        int rowo = c - 512;
        bool do_silu = (c >= 608 && c < 612);
        bool do_sig  = (c < 576) || (c == 612);
#pragma unroll
        for (int j = 0; j < 2; ++j) {
          float z = acc[i][j][r] + bia;
          if (do_silu) z = siluf_(z);
          else if (do_sig) z = sigmoidf_(z);
          projS[(size_t)rowo * PTOT + p0 + wc * 32 + j * 16 + lm] = z;
        }
      } else {
#pragma unroll
        for (int j = 0; j < 2; ++j) {
          float z = siluf_(acc[i][j][r] + bia);
          projBC[(size_t)c * PTOT + p0 + wc * 32 + j * 16 + lm] = f2bf(z);
        }
      }
    }
  }
}

// ---------------------------------------------------------------------------
// Iteration kernel: one block per (n-pair, r, batch), 12 iterations fused.
// ---------------------------------------------------------------------------
__global__ __launch_bounds__(256) void iter_kernel(
    const ushort_t* __restrict__ projBC, const float* __restrict__ projS,
    const float* __restrict__ conv_w, const float* __restrict__ conv_b,
    ushort_t* __restrict__ HgBf) {
  const int n2 = blockIdx.x;   // channel pair 0..31
  const int r  = blockIdx.y;   // 0..3
  const int b  = blockIdx.z;   // 0..15
  const int n0 = 2 * n2, n1 = n0 + 1;
  const int tid = threadIdx.x;
  const int bh = tid >> 4, bw = tid & 15;   // 3x3 strip coords
  const int pbase = b * IMG;

  __shared__ float2 HS[2][50 * 51];   // [buf][(h+1)*51 + (w+1)], zero halo

  float w0[9], w1[9];
#pragma unroll
  for (int t = 0; t < 9; ++t) {
    w0[t] = rfl(conv_w[t * 64 + n0]);
    w1[t] = rfl(conv_w[t * 64 + n1]);
  }
  const float cvb0 = rfl(conv_b[n0]), cvb1 = rfl(conv_b[n1]);

  {
    float4 zz = {0.f, 0.f, 0.f, 0.f};
    float4* z = (float4*)&HS[0][0];
#pragma unroll
    for (int u = 0; u < 10; ++u) {
      int q = tid + 256 * u;
      if (q < 2550) z[q] = zz;
    }
  }

  const ushort_t* rowB0 = projBC + (size_t)(n0 * 4 + r) * PTOT + pbase;
  const ushort_t* rowB1 = projBC + (size_t)(n1 * 4 + r) * PTOT + pbase;
  const ushort_t* rowC0 = projBC + (size_t)(256 + n0 * 4 + r) * PTOT + pbase;
  const ushort_t* rowC1 = projBC + (size_t)(256 + n1 * 4 + r) * PTOT + pbase;
  const float* rowA0 = projS + (size_t)n0 * PTOT + pbase;          // alpha
  const float* rowA1 = projS + (size_t)n1 * PTOT + pbase;
  const float* rowTh = projS + (size_t)(64 + n2) * PTOT + pbase;   // theta
  const float* rowXv = projS + (size_t)(96 + r) * PTOT + pbase;    // X
  const float* rowGm = projS + (size_t)100 * PTOT + pbase;         // gamma

  float be0[9], be1[9], cb[9], sb[9], al0[9], al1[9], gmv[9];
#pragma unroll
  for (int s = 0; s < 9; ++s) {
    int dy = s / 3, dx = s - 3 * dy;
    int i = (3 * bh + dy) * 48 + 3 * bw + dx;
    float sn, cn;
    __sincosf(rowTh[i], &sn, &cn);
    cb[s] = cn; sb[s] = sn;
    float B0 = bf2f(rowB0[i]), B1 = bf2f(rowB1[i]), X = rowXv[i];
    be0[s] = (B0 * cn - B1 * sn) * X;   // inj at angle theta (iteration 0)
    be1[s] = (B0 * sn + B1 * cn) * X;
    al0[s] = rowA0[i]; al1[s] = rowA1[i];
    gmv[s] = rowGm[i];
  }
  __syncthreads();

  int cur = 0;
  for (int it = 0; it < 12; ++it) {
    float a0[9], a1[9];
#pragma unroll
    for (int s = 0; s < 9; ++s) { a0[s] = cvb0; a1[s] = cvb1; }
#pragma unroll
    for (int yy = 0; yy < 5; ++yy) {
      float2 row[5];
#pragma unroll
      for (int xx = 0; xx < 5; ++xx)
        row[xx] = HS[cur][(3 * bh + yy) * 51 + 3 * bw + xx];
#pragma unroll
      for (int dy = 0; dy < 3; ++dy) {
        int ty = yy - dy;
        if (ty < 0 || ty > 2) continue;
#pragma unroll
        for (int dx = 0; dx < 3; ++dx)
#pragma unroll
          for (int tx = 0; tx < 3; ++tx) {
            a0[dy * 3 + dx] += row[dx + tx].x * w0[ty * 3 + tx];
            a1[dy * 3 + dx] += row[dx + tx].y * w1[ty * 3 + tx];
          }
      }
    }
#pragma unroll
    for (int s = 0; s < 9; ++s) {
      int dy = s / 3, dx = s - 3 * dy;
      float h0, h1;
      if (it == 0) {
        h0 = al0[s] * a0[s] + be0[s];
        h1 = al1[s] * a1[s] + be1[s];
      } else {
        float p0 = be0[s] * cb[s] + be1[s] * sb[s];
        float p1 = be1[s] * cb[s] - be0[s] * sb[s];
        float g = gmv[s];
        h0 = al0[s] * (a0[s] + (1.f - g) * p0) + g * be0[s];
        h1 = al1[s] * (a1[s] + (1.f - g) * p1) + g * be1[s];
      }
      float2 hw; hw.x = h0; hw.y = h1;
      HS[cur ^ 1][(3 * bh + dy + 1) * 51 + (3 * bw + dx + 1)] = hw;
      if (it < 11) {
        float nb0 = be0[s] * cb[s] - be1[s] * sb[s];
        float nb1 = be0[s] * sb[s] + be1[s] * cb[s];
        be0[s] = nb0; be1[s] = nb1;
      }
    }
    __syncthreads();
    cur ^= 1;
  }

  ushort_t* outRow0 = HgBf + (size_t)(r * 64 + n0) * PTOT + pbase;
  ushort_t* outRow1 = HgBf + (size_t)(r * 64 + n1) * PTOT + pbase;
#pragma unroll
  for (int s = 0; s < 9; ++s) {
    int dy = s / 3, dx = s - 3 * dy;
    int i = (3 * bh + dy) * 48 + 3 * bw + dx;
    float c2 = cb[s] * cb[s] - sb[s] * sb[s], s2 = 2.f * cb[s] * sb[s];
    float c4 = c2 * c2 - s2 * s2,             s4 = 2.f * c2 * s2;
    float c8 = c4 * c4 - s4 * s4,             s8 = 2.f * c4 * s4;
    float c12 = c8 * c4 - s8 * s4,            s12 = c8 * s4 + s8 * c4;
    float C0 = bf2f(rowC0[i]), C1 = bf2f(rowC1[i]);
    float cr0 = C0 * c12 - C1 * s12;
    float cr1 = C0 * s12 + C1 * c12;
    float2 hv = HS[cur][(3 * bh + dy + 1) * 51 + (3 * bw + dx + 1)];
    outRow0[i] = f2bf(cr0 * hv.x);
    outRow1[i] = f2bf(cr1 * hv.y);
  }
}

// ---------------------------------------------------------------------------
// transpose: HgBf [k][p] bf16 -> Hbf [p][k] bf16 (f32 64x65 LDS tile).
// ---------------------------------------------------------------------------
__global__ __launch_bounds__(256) void transpose_cvt(
    const ushort_t* __restrict__ HgBf, ushort_t* __restrict__ Hbf) {
  __shared__ float T[64][65];
  const int tid = threadIdx.x;
  const int p0 = blockIdx.x * 64;
  const int k0 = blockIdx.y * 64;
  {
    int row = tid >> 2, q = tid & 3;
    const ushort_t* src = &HgBf[(size_t)(k0 + row) * PTOT + p0 + q * 16];
    uint4 u0 = *(const uint4*)src;
    uint4 u1 = *(const uint4*)(src + 8);
    const uint_t* up = (const uint_t*)&u0;
#pragma unroll
    for (int t = 0; t < 4; ++t) {
      T[row][q * 16 + 2 * t]     = bf2f((ushort_t)(up[t] & 0xffffu));
      T[row][q * 16 + 2 * t + 1] = bf2f((ushort_t)(up[t] >> 16));
    }
    const uint_t* vp = (const uint_t*)&u1;
#pragma unroll
    for (int t = 0; t < 4; ++t) {
      T[row][q * 16 + 8 + 2 * t]     = bf2f((ushort_t)(vp[t] & 0xffffu));
      T[row][q * 16 + 8 + 2 * t + 1] = bf2f((ushort_t)(vp[t] >> 16));
    }
  }
  __syncthreads();
  {
    int pr = tid >> 2, kq = tid & 3;
    uint_t Hw[8];
#pragma unroll
    for (int q = 0; q < 8; ++q)
      Hw[q] = cvt2_hi(T[kq * 16 + 2 * q][pr], T[kq * 16 + 2 * q + 1][pr]);
    size_t off = (size_t)(p0 + pr) * 256 + k0 + kq * 16;
    *(uint4*)&Hbf[off]     = make_uint4(Hw[0], Hw[1], Hw[2], Hw[3]);
    *(uint4*)&Hbf[off + 8] = make_uint4(Hw[4], Hw[5], Hw[6], Hw[7]);
  }
}

// ---------------------------------------------------------------------------
// GEMM C: 512 threads (8 waves of 64x32), glds 2-buffer, XOR maps.
// ---------------------------------------------------------------------------
__global__ __launch_bounds__(512, 6) void gemm_out_glds(
    const ushort_t* __restrict__ Hbf, const ushort_t* __restrict__ WoT,
    const float* __restrict__ b_out, float* __restrict__ out) {
  __shared__ ushort_t As[2][4096];   // Hg tiles
  __shared__ ushort_t Bs[2][4096];   // W_out^T tiles
  const int tid = threadIdx.x;
  const int lane = tid & 63, wv = tid >> 6;
  const int wr = wv >> 2, wc = wv & 3;
  const int lk = lane >> 4, lm = lane & 15;
  int lin = blockIdx.x;                    // 0..1727, 1728 = 8*216
  int id2 = (lin & 7) * 216 + (lin >> 3);
  const int jblk = id2 % 6, pblk = id2 / 6;
  const int j0 = jblk * 128, p0 = pblk * 128;

  f32x4 acc[4][2];
#pragma unroll
  for (int i = 0; i < 4; ++i)
#pragma unroll
    for (int j = 0; j < 2; ++j) acc[i][j] = (f32x4)0.f;

  auto stage = [&](int buf, int kidx) {
    const int k0 = kidx * 32;
    {
      int mb = __builtin_amdgcn_readfirstlane(wv * 64);
      int m = mb + lane;
      int row = m >> 2, sp = m & 3;
      int g = sp ^ ((row >> 1) & 3);
      glds16(&Hbf[(size_t)(p0 + row) * 256 + k0 + g * 8],
             (void*)&As[buf][mb * 8]);
    }
    {
      int mb = __builtin_amdgcn_readfirstlane(wv * 64);
      int m = mb + lane;
      int row = m >> 2, sp = m & 3;
      int g = sp ^ ((row >> 1) & 3);
      glds16(&WoT[(size_t)(j0 + row) * 256 + k0 + g * 8],
             (void*)&Bs[buf][mb * 8]);
    }
  };

  stage(0, 0);
  __syncthreads();

  for (int kidx = 0; kidx < 8; ++kidx) {
    const int cur = kidx & 1;
    if (kidx + 1 < 8) stage(cur ^ 1, kidx + 1);
    bfx8 ah[4], bh[2];
#pragma unroll
    for (int f = 0; f < 4; ++f) {
      int ra = wr * 64 + f * 16 + lm;
      int sa = lk ^ ((ra >> 1) & 3);
      ah[f] = *(const bfx8*)&As[cur][(ra * 4 + sa) * 8];
    }
#pragma unroll
    for (int n = 0; n < 2; ++n) {
      int rb = wc * 32 + n * 16 + lm;
      int sb2 = lk ^ ((rb >> 1) & 3);
      bh[n] = *(const bfx8*)&Bs[cur][(rb * 4 + sb2) * 8];
    }
#pragma unroll
    for (int i = 0; i < 4; ++i)
#pragma unroll
      for (int j = 0; j < 2; ++j)
        acc[i][j] = MFMA_BF16(ah[i], bh[j], acc[i][j]);
    __syncthreads();
  }

  float bo[2];
#pragma unroll
  for (int jj = 0; jj < 2; ++jj) bo[jj] = b_out[j0 + wc * 32 + jj * 16 + lm];
#pragma unroll
  for (int i = 0; i < 4; ++i) {
#pragma unroll
    for (int r = 0; r < 4; ++r) {
      int p = p0 + wr * 64 + i * 16 + lk * 4 + r;
      size_t rowoff = (size_t)p * DIM;
#pragma unroll
      for (int jj = 0; jj < 2; ++jj) {
        out[rowoff + j0 + wc * 32 + jj * 16 + lm] =
            siluf_(acc[i][jj][r] + bo[jj]);
      }
    }
  }
}

// ---------------------------------------------------------------------------
extern "C" void kernel_launch(void* const* d_in, const int* in_sizes, int n_in,
                              void* d_out, int out_size, void* d_ws, size_t ws_size,
                              hipStream_t stream) {
  const float* x      = (const float*)d_in[0];
  const float* W_B    = (const float*)d_in[1];
  const float* b_B    = (const float*)d_in[2];
  const float* W_C    = (const float*)d_in[3];
  const float* b_C    = (const float*)d_in[4];
  const float* W_X    = (const float*)d_in[5];
  const float* b_X    = (const float*)d_in[6];
  const float* W_dec  = (const float*)d_in[7];
  const float* b_dec  = (const float*)d_in[8];
  const float* W_th   = (const float*)d_in[9];
  const float* b_th   = (const float*)d_in[10];
  const float* W_lam  = (const float*)d_in[11];
  const float* b_lam  = (const float*)d_in[12];
  const float* B_bias = (const float*)d_in[13];
  const float* C_bias = (const float*)d_in[14];
  const float* conv_w = (const float*)d_in[15];
  const float* conv_b = (const float*)d_in[16];
  const float* W_out  = (const float*)d_in[17];
  const float* b_out  = (const float*)d_in[18];
  float* out = (float*)d_out;

  // workspace layout (~93 MB, under proven 131 MB):
  //  weights 2.4 | projBC bf16 37.75 | projS f32 15.3 | HgBf 18.9 | Hbf 18.9
  ushort_t* WhiT   = (ushort_t*)d_ws;                     // 640*768
  ushort_t* WloT   = WhiT + (size_t)NCOLS * DIM;
  ushort_t* WoT    = WloT + (size_t)NCOLS * DIM;          // 768*256
  float* bias_all  = (float*)(WoT + (size_t)DIM * 256);   // 640
  ushort_t* projBC = (ushort_t*)(bias_all + NCOLS);       // 512*36864 bf16
  float* projS     = (float*)(projBC + (size_t)512 * PTOT);  // 104*36864 f32
  ushort_t* HgBf   = (ushort_t*)(projS + (size_t)104 * PTOT); // 256*36864 bf16
  ushort_t* Hbf    = HgBf + (size_t)256 * PTOT;           // 36864*256 bf16

  const int pack_elems = NCOLS * DIM + DIM * 256;
  pack_kernel<<<(pack_elems + 255) / 256, 256, 0, stream>>>(
      W_B, W_C, W_dec, W_th, W_X, W_lam,
      b_B, b_C, b_dec, b_th, b_X, b_lam, B_bias, C_bias, W_out,
      WhiT, WloT, WoT, bias_all);

  gemm_proj_glds<0><<<dim3(4 * NPBLK), 512, 0, stream>>>(
      x, WhiT, WloT, bias_all, projBC, projS);
  gemm_proj_glds<1><<<dim3(NPBLK), 512, 0, stream>>>(
      x, WhiT, WloT, bias_all, projBC, projS);

  iter_kernel<<<dim3(32, 4, 16), 256, 0, stream>>>(
      projBC, projS, conv_w, conv_b, HgBf);

  transpose_cvt<<<dim3(PTOT / 64, 4), 256, 0, stream>>>(HgBf, Hbf);

  gemm_out_glds<<<dim3(6 * NPBLK), 512, 0, stream>>>(
      Hbf, WoT, b_out, out);
}